// Round 8
// baseline (208.877 us; speedup 1.0000x reference)
//
#include <hip/hip_runtime.h>
#include <hip/hip_bf16.h>

// Fused: [LN + weight transposes] -> QKV proj (V transposed) -> attention -> out proj + bias.

typedef _Float16 f16x8 __attribute__((ext_vector_type(8)));
typedef _Float16 f16x4 __attribute__((ext_vector_type(4)));
typedef float    f32x4 __attribute__((ext_vector_type(4)));

#define DIM   1024
#define NH    16
#define HD2   64
#define SEQ   2048
#define ROWS  4096   // b*n = 2*2048
#define QKVN  3072

__device__ __forceinline__ void async_copy16(void* lds, const void* gsrc) {
    __builtin_amdgcn_global_load_lds(
        (const __attribute__((address_space(1))) unsigned int*)gsrc,
        (__attribute__((address_space(3))) unsigned int*)lds, 16, 0, 0);
}

// ---------------- prologue: LN (blocks 0..4095) + transpose w_qkv + transpose w_out ----------------
__global__ __launch_bounds__(256) void prologue_kernel(
    const float* __restrict__ x, const float* __restrict__ gamma,
    const float* __restrict__ beta, _Float16* __restrict__ xn,
    const float* __restrict__ w_qkv, _Float16* __restrict__ wqkvT,
    const float* __restrict__ w_out, _Float16* __restrict__ woutT) {
    __shared__ float smem[32 * 33];
    const int bid = blockIdx.x;
    const int t = threadIdx.x;
    if (bid < ROWS) {
        const int row = bid;
        const float4 v = reinterpret_cast<const float4*>(x + (size_t)row * DIM)[t];
        float s1 = v.x + v.y + v.z + v.w;
        float s2 = v.x * v.x + v.y * v.y + v.z * v.z + v.w * v.w;
        for (int off = 32; off; off >>= 1) {
            s1 += __shfl_down(s1, off);
            s2 += __shfl_down(s2, off);
        }
        const int wv = t >> 6, lane = t & 63;
        if (lane == 0) { smem[wv * 2] = s1; smem[wv * 2 + 1] = s2; }
        __syncthreads();
        s1 = smem[0] + smem[2] + smem[4] + smem[6];
        s2 = smem[1] + smem[3] + smem[5] + smem[7];
        const float mu = s1 * (1.0f / DIM);
        const float var = s2 * (1.0f / DIM) - mu * mu;
        const float rstd = rsqrtf(var + 1e-5f);
        const float4 g = reinterpret_cast<const float4*>(gamma)[t];
        const float4 bb = reinterpret_cast<const float4*>(beta)[t];
        f16x4 o;
        o[0] = (_Float16)((v.x - mu) * rstd * g.x + bb.x);
        o[1] = (_Float16)((v.y - mu) * rstd * g.y + bb.y);
        o[2] = (_Float16)((v.z - mu) * rstd * g.z + bb.z);
        o[3] = (_Float16)((v.w - mu) * rstd * g.w + bb.w);
        reinterpret_cast<f16x4*>(xn + (size_t)row * DIM)[t] = o;
        return;
    }
    const float* in;
    _Float16* out;
    int C, bx, by;
    if (bid < ROWS + (QKVN / 32) * (DIM / 32)) {
        const int q = bid - ROWS;
        in = w_qkv; out = wqkvT; C = QKVN;
        bx = q % (QKVN / 32); by = q / (QKVN / 32);
    } else {
        const int q = bid - ROWS - (QKVN / 32) * (DIM / 32);
        in = w_out; out = woutT; C = DIM;
        bx = q % (DIM / 32); by = q / (DIM / 32);
    }
    const int R = DIM;
    const int c0 = bx * 32, r0 = by * 32;
    const int tx = t & 31, ty = t >> 5;
    float (*tile)[33] = reinterpret_cast<float(*)[33]>(smem);
#pragma unroll
    for (int i = 0; i < 4; i++)
        tile[ty + i * 8][tx] = in[(size_t)(r0 + ty + i * 8) * C + c0 + tx];
    __syncthreads();
#pragma unroll
    for (int i = 0; i < 4; i++)
        out[(size_t)(c0 + ty + i * 8) * R + r0 + tx] = (_Float16)tile[tx][ty + i * 8];
}

// ------------- QKV GEMM: xn (4096x1024) * wqkvT (3072x1024), 2-phase dbuf, XCD-chunked -------------
__global__ __launch_bounds__(256) void gemm_qkv_kernel(
    const _Float16* __restrict__ A, const _Float16* __restrict__ Bt,
    _Float16* __restrict__ qk, _Float16* __restrict__ vT, int K) {
    __shared__ _Float16 Al[2][128 * 32];
    __shared__ _Float16 Bl[2][128 * 32];
    const int t = threadIdx.x, wv = t >> 6, lane = t & 63;
    const int lg = lane >> 4, lr = lane & 15;
    const int wr = wv >> 1, wc = wv & 1;
    // XCD-chunked: each XCD owns 3 consecutive B-panels (bx), streams A (by)
    const int id = blockIdx.x;
    const int nid = (id & 7) * 96 + (id >> 3);       // 768 = 8 x 96
    const int bx = nid / 32, by = nid % 32;
    const int m0 = by * 128, n0 = bx * 128;

    f32x4 acc[4][4] = {};

    const int srow = t >> 2, sk = (t & 3) * 8;
    const _Float16* Ag0 = A + (size_t)(m0 + srow) * K + sk;
    const _Float16* Bg0 = Bt + (size_t)(n0 + srow) * K + sk;

    auto STAGE = [&](int buf, int k0) {
        _Float16* Alw = &Al[buf][wv * 512];
        _Float16* Blw = &Bl[buf][wv * 512];
        async_copy16(Alw,        Ag0 + k0);
        async_copy16(Alw + 2048, Ag0 + (size_t)64 * K + k0);
        async_copy16(Blw,        Bg0 + k0);
        async_copy16(Blw + 2048, Bg0 + (size_t)64 * K + k0);
    };

    STAGE(0, 0);
    asm volatile("s_waitcnt vmcnt(0)" ::: "memory");
    __builtin_amdgcn_s_barrier();
    int cur = 0;
    for (int k0 = 0; k0 < K; k0 += 32) {
        if (k0 + 32 < K) STAGE(cur ^ 1, k0 + 32);
        const _Float16* Ab = &Al[cur][0];
        const _Float16* Bb = &Bl[cur][0];
        f16x8 af[4], bfr[4];
#pragma unroll
        for (int m = 0; m < 4; m++)
            af[m] = *reinterpret_cast<const f16x8*>(&Ab[(wr * 64 + m * 16 + lr) * 32 + lg * 8]);
#pragma unroll
        for (int n = 0; n < 4; n++)
            bfr[n] = *reinterpret_cast<const f16x8*>(&Bb[(wc * 64 + n * 16 + lr) * 32 + lg * 8]);
#pragma unroll
        for (int m = 0; m < 4; m++)
#pragma unroll
            for (int n = 0; n < 4; n++)
                acc[m][n] = __builtin_amdgcn_mfma_f32_16x16x32_f16(af[m], bfr[n], acc[m][n], 0, 0, 0);
        asm volatile("s_waitcnt vmcnt(0)" ::: "memory");
        __builtin_amdgcn_s_barrier();
        cur ^= 1;
    }

    if (n0 < 2 * DIM) {
#pragma unroll
        for (int m = 0; m < 4; m++) {
            const int row = m0 + wr * 64 + m * 16 + lg * 4;
#pragma unroll
            for (int n = 0; n < 4; n++) {
                const int col = n0 + wc * 64 + n * 16 + lr;
#pragma unroll
                for (int jj = 0; jj < 4; jj++)
                    qk[(size_t)(row + jj) * 2048 + col] = (_Float16)acc[m][n][jj];
            }
        }
    } else {
#pragma unroll
        for (int m = 0; m < 4; m++) {
            const int row = m0 + wr * 64 + m * 16 + lg * 4;
            const int b = row >> 11, nn = row & 2047;
#pragma unroll
            for (int n = 0; n < 4; n++) {
                const int vcol = n0 + wc * 64 + n * 16 + lr - 2 * DIM;
                f16x4 pk;
#pragma unroll
                for (int jj = 0; jj < 4; jj++) pk[jj] = (_Float16)acc[m][n][jj];
                *reinterpret_cast<f16x4*>(&vT[(size_t)(b * 1024 + vcol) * SEQ + nn]) = pk;
            }
        }
    }
}

// ------------- out-proj GEMM: attn (4096x1024) * woutT (1024x1024) + bias -> f32 -------------
// tile 128(M) x 64(N), 2-phase dbuf, XCD-chunked; grid 512 blocks.
__global__ __launch_bounds__(256) void gemm_out_kernel(
    const _Float16* __restrict__ A, const _Float16* __restrict__ Bt,
    float* __restrict__ C, const float* __restrict__ bias, int N, int K) {
    __shared__ _Float16 Al[2][128 * 32];
    __shared__ _Float16 Bl[2][64 * 32];
    const int t = threadIdx.x, wv = t >> 6, lane = t & 63;
    const int lg = lane >> 4, lr = lane & 15;
    const int wr = wv >> 1, wc = wv & 1;
    const int id = blockIdx.x;
    const int nid = (id & 7) * 64 + (id >> 3);       // 512 = 8 x 64
    const int bx = nid / 32, by = nid % 32;
    const int m0 = by * 128, n0 = bx * 64;

    f32x4 acc[4][2] = {};

    const int srow = t >> 2, sk = (t & 3) * 8;
    const _Float16* Ag0 = A + (size_t)(m0 + srow) * K + sk;
    const _Float16* Bg0 = Bt + (size_t)(n0 + srow) * K + sk;

    auto STAGE = [&](int buf, int k0) {
        _Float16* Alw = &Al[buf][wv * 512];
        _Float16* Blw = &Bl[buf][wv * 512];
        async_copy16(Alw,        Ag0 + k0);
        async_copy16(Alw + 2048, Ag0 + (size_t)64 * K + k0);
        async_copy16(Blw,        Bg0 + k0);
    };

    STAGE(0, 0);
    asm volatile("s_waitcnt vmcnt(0)" ::: "memory");
    __builtin_amdgcn_s_barrier();
    int cur = 0;
    for (int k0 = 0; k0 < K; k0 += 32) {
        if (k0 + 32 < K) STAGE(cur ^ 1, k0 + 32);
        const _Float16* Ab = &Al[cur][0];
        const _Float16* Bb = &Bl[cur][0];
        f16x8 af[4], bfr[2];
#pragma unroll
        for (int m = 0; m < 4; m++)
            af[m] = *reinterpret_cast<const f16x8*>(&Ab[(wr * 64 + m * 16 + lr) * 32 + lg * 8]);
#pragma unroll
        for (int n = 0; n < 2; n++)
            bfr[n] = *reinterpret_cast<const f16x8*>(&Bb[(wc * 32 + n * 16 + lr) * 32 + lg * 8]);
#pragma unroll
        for (int m = 0; m < 4; m++)
#pragma unroll
            for (int n = 0; n < 2; n++)
                acc[m][n] = __builtin_amdgcn_mfma_f32_16x16x32_f16(af[m], bfr[n], acc[m][n], 0, 0, 0);
        asm volatile("s_waitcnt vmcnt(0)" ::: "memory");
        __builtin_amdgcn_s_barrier();
        cur ^= 1;
    }

#pragma unroll
    for (int m = 0; m < 4; m++) {
        const int row = m0 + wr * 64 + m * 16 + lg * 4;
#pragma unroll
        for (int n = 0; n < 2; n++) {
            const int col = n0 + wc * 32 + n * 16 + lr;
            const float bo = bias[col];
#pragma unroll
            for (int jj = 0; jj < 4; jj++)
                C[(size_t)(row + jj) * N + col] = acc[m][n][jj] + bo;
        }
    }
}

// ------------- flash attention: QBLK=64, lane-local P (permuted-key PV), dbuf K/V, pad-76 -------------
// grid 1024 blocks (XCD-swizzled), 4 waves; wave owns 16 q rows; KV tile 64. 4 blocks/CU.
__global__ __launch_bounds__(256, 4) void attn_fa_kernel(
    const _Float16* __restrict__ qk, const _Float16* __restrict__ vT,
    _Float16* __restrict__ attn) {
    const int id = blockIdx.x;
    const int nid = (id & 7) * 128 + (id >> 3);     // bijective: 1024 = 8 XCD x 128
    const int bh = nid >> 5, b = bh >> 4, h = bh & 15;
    const int q0 = (nid & 31) * 64;
    const int t = threadIdx.x, wv = t >> 6, lane = t & 63;
    const int lg = lane >> 4, lr = lane & 15;

    __shared__ _Float16 Kl[2][64][76];    // K tile [key][d], pad 76 (stride 152B: conflict-free)
    __shared__ _Float16 Vt[2][64][76];    // V^T tile [d][key]

    // Q fragment (B operand: col q=lr, k=d), pre-scaled by 1/8
    const _Float16* qp = qk + (size_t)(b * SEQ + q0 + wv * 16 + lr) * 2048 + h * HD2;
    f16x8 qf0 = *reinterpret_cast<const f16x8*>(qp + lg * 8);
    f16x8 qf1 = *reinterpret_cast<const f16x8*>(qp + 32 + lg * 8);
    qf0 = qf0 * (_Float16)0.125f;
    qf1 = qf1 * (_Float16)0.125f;

    f32x4 o[4] = {};                       // O^T: lane holds d = dn*16+lg*4+jj for q = lr
    float mrun = -INFINITY, lrun = 0.f;

    const int sr = t >> 3, sc = (t & 7) * 8;
    const _Float16* kbase = qk + (size_t)(b * SEQ + sr) * 2048 + DIM + h * HD2 + sc;
    const _Float16* vbase = vT + (size_t)(bh * HD2 + sr) * SEQ + sc;

    // prologue: tile 0 -> buf 0; prefetch tile 1 into regs
    f16x8 rk0 = *reinterpret_cast<const f16x8*>(kbase);
    f16x8 rk1 = *reinterpret_cast<const f16x8*>(kbase + (size_t)32 * 2048);
    f16x8 rv0 = *reinterpret_cast<const f16x8*>(vbase);
    f16x8 rv1 = *reinterpret_cast<const f16x8*>(vbase + (size_t)32 * SEQ);
    *reinterpret_cast<f16x8*>(&Kl[0][sr][sc])      = rk0;
    *reinterpret_cast<f16x8*>(&Kl[0][sr + 32][sc]) = rk1;
    *reinterpret_cast<f16x8*>(&Vt[0][sr][sc])      = rv0;
    *reinterpret_cast<f16x8*>(&Vt[0][sr + 32][sc]) = rv1;
    rk0 = *reinterpret_cast<const f16x8*>(kbase + (size_t)64 * 2048);
    rk1 = *reinterpret_cast<const f16x8*>(kbase + (size_t)96 * 2048);
    rv0 = *reinterpret_cast<const f16x8*>(vbase + 64);
    rv1 = *reinterpret_cast<const f16x8*>(vbase + (size_t)32 * SEQ + 64);
    asm volatile("s_waitcnt lgkmcnt(0)" ::: "memory");
    __builtin_amdgcn_s_barrier();

    int p = 0;
    for (int kv0 = 0; kv0 < SEQ; kv0 += 64, p ^= 1) {
        if (kv0 + 64 < SEQ) {
            // write tile t+1 (in regs) into buf p^1; then prefetch tile t+2
            *reinterpret_cast<f16x8*>(&Kl[p ^ 1][sr][sc])      = rk0;
            *reinterpret_cast<f16x8*>(&Kl[p ^ 1][sr + 32][sc]) = rk1;
            *reinterpret_cast<f16x8*>(&Vt[p ^ 1][sr][sc])      = rv0;
            *reinterpret_cast<f16x8*>(&Vt[p ^ 1][sr + 32][sc]) = rv1;
            if (kv0 + 128 < SEQ) {
                const _Float16* kp = kbase + (size_t)(kv0 + 128) * 2048;
                const _Float16* vp = vbase + (kv0 + 128);
                rk0 = *reinterpret_cast<const f16x8*>(kp);
                rk1 = *reinterpret_cast<const f16x8*>(kp + (size_t)32 * 2048);
                rv0 = *reinterpret_cast<const f16x8*>(vp);
                rv1 = *reinterpret_cast<const f16x8*>(vp + (size_t)32 * SEQ);
            }
        }

        // ---- S^T = K Q^T : lane holds keys {n*16+lg*4+jj} for q=lr
        f32x4 s[4];
#pragma unroll
        for (int n = 0; n < 4; n++) {
            f16x8 kf0 = *reinterpret_cast<const f16x8*>(&Kl[p][n * 16 + lr][lg * 8]);
            f16x8 kf1 = *reinterpret_cast<const f16x8*>(&Kl[p][n * 16 + lr][32 + lg * 8]);
            f32x4 z = {0.f, 0.f, 0.f, 0.f};
            __builtin_amdgcn_s_setprio(1);
            z = __builtin_amdgcn_mfma_f32_16x16x32_f16(kf0, qf0, z, 0, 0, 0);
            z = __builtin_amdgcn_mfma_f32_16x16x32_f16(kf1, qf1, z, 0, 0, 0);
            __builtin_amdgcn_s_setprio(0);
            s[n] = z;
        }

        // ---- online softmax (defer-max): in-lane over 16 keys + 2 shfls
        float m1 = fmaxf(fmaxf(s[0][0], s[0][1]), fmaxf(s[0][2], s[0][3]));
#pragma unroll
        for (int n = 1; n < 4; n++)
            m1 = fmaxf(m1, fmaxf(fmaxf(s[n][0], s[n][1]), fmaxf(s[n][2], s[n][3])));
        m1 = fmaxf(m1, __shfl_xor(m1, 16));
        m1 = fmaxf(m1, __shfl_xor(m1, 32));
        if (!__all(m1 - mrun <= 8.f)) {
            const float mnew = fmaxf(mrun, m1);
            const float corr = __expf(mrun - mnew);
            mrun = mnew;
            lrun *= corr;
#pragma unroll
            for (int dn = 0; dn < 4; dn++) o[dn] *= corr;
        }
        float rsum = 0.f;
#pragma unroll
        for (int n = 0; n < 4; n++)
#pragma unroll
            for (int jj = 0; jj < 4; jj++) {
                const float pv = __expf(s[n][jj] - mrun);
                s[n][jj] = pv;
                rsum += pv;
            }
        rsum += __shfl_xor(rsum, 16);
        rsum += __shfl_xor(rsum, 32);
        lrun += rsum;

        // ---- lane-local P fragments: mfma m consumes key chunks {2m,2m+1}
        f16x8 pa[2];
#pragma unroll
        for (int m = 0; m < 2; m++) {
            f16x8 pv;
#pragma unroll
            for (int jj = 0; jj < 4; jj++) {
                pv[jj]     = (_Float16)s[2 * m][jj];
                pv[4 + jj] = (_Float16)s[2 * m + 1][jj];
            }
            pa[m] = pv;
        }

        // ---- O^T += V^T P with the SAME key permutation on V (4x b64 per frag pair)
#pragma unroll
        for (int dn = 0; dn < 4; dn++) {
            const _Float16* vr = &Vt[p][dn * 16 + lr][0];
            f16x4 va0 = *reinterpret_cast<const f16x4*>(vr + lg * 4);         // chunk 0
            f16x4 va1 = *reinterpret_cast<const f16x4*>(vr + 16 + lg * 4);    // chunk 1
            f16x4 vb0 = *reinterpret_cast<const f16x4*>(vr + 32 + lg * 4);    // chunk 2
            f16x4 vb1 = *reinterpret_cast<const f16x4*>(vr + 48 + lg * 4);    // chunk 3
            f16x8 vf0, vf1;
#pragma unroll
            for (int j = 0; j < 4; j++) {
                vf0[j] = va0[j]; vf0[4 + j] = va1[j];
                vf1[j] = vb0[j]; vf1[4 + j] = vb1[j];
            }
            __builtin_amdgcn_s_setprio(1);
            o[dn] = __builtin_amdgcn_mfma_f32_16x16x32_f16(vf0, pa[0], o[dn], 0, 0, 0);
            o[dn] = __builtin_amdgcn_mfma_f32_16x16x32_f16(vf1, pa[1], o[dn], 0, 0, 0);
            __builtin_amdgcn_s_setprio(0);
        }
        asm volatile("s_waitcnt lgkmcnt(0)" ::: "memory");   // my LDS reads landed
        __builtin_amdgcn_s_barrier();
    }

    // epilogue: O[q][d] = O^T/l ; lane's q = lr, d = dn*16+lg*4+jj (f16x4 per dn)
    const float inv = 1.0f / lrun;
    const size_t orow = (size_t)(b * SEQ + q0 + wv * 16 + lr);
#pragma unroll
    for (int dn = 0; dn < 4; dn++) {
        f16x4 pk;
#pragma unroll
        for (int jj = 0; jj < 4; jj++) pk[jj] = (_Float16)(o[dn][jj] * inv);
        *reinterpret_cast<f16x4*>(&attn[orow * DIM + h * HD2 + dn * 16 + lg * 4]) = pk;
    }
}

extern "C" void kernel_launch(void* const* d_in, const int* in_sizes, int n_in,
                              void* d_out, int out_size, void* d_ws, size_t ws_size,
                              hipStream_t stream) {
    const float* x     = (const float*)d_in[0];
    const float* gamma = (const float*)d_in[1];
    const float* beta  = (const float*)d_in[2];
    const float* w_qkv = (const float*)d_in[3];
    const float* w_out = (const float*)d_in[4];
    const float* b_out = (const float*)d_in[5];
    float* out = (float*)d_out;

    _Float16* ws    = (_Float16*)d_ws;
    _Float16* xn    = ws;                                  // 4096*1024
    _Float16* wqkvT = xn + (size_t)ROWS * DIM;             // 3072*1024
    _Float16* woutT = wqkvT + (size_t)QKVN * DIM;          // 1024*1024
    _Float16* qk    = woutT + (size_t)DIM * DIM;           // 4096*2048
    _Float16* vT    = qk + (size_t)ROWS * 2048;            // (32*64)*2048
    _Float16* attnb = xn;                                  // reuse xn region

    const int pro_blocks = ROWS + (QKVN / 32) * (DIM / 32) + (DIM / 32) * (DIM / 32);
    prologue_kernel<<<pro_blocks, 256, 0, stream>>>(x, gamma, beta, xn, w_qkv, wqkvT, w_out, woutT);
    gemm_qkv_kernel<<<768, 256, 0, stream>>>(xn, wqkvT, qk, vT, DIM);
    attn_fa_kernel<<<1024, 256, 0, stream>>>(qk, vT, attnb);
    gemm_out_kernel<<<512, 256, 0, stream>>>(attnb, woutT, out, b_out, DIM, DIM);
}

// Round 9
// 200.808 us; speedup vs baseline: 1.0402x; 1.0402x over previous
//
#include <hip/hip_runtime.h>
#include <hip/hip_bf16.h>

// Fused: [LN + weight transposes] -> QKV proj (V transposed) -> attention -> out proj + bias.

typedef _Float16 f16x8 __attribute__((ext_vector_type(8)));
typedef _Float16 f16x4 __attribute__((ext_vector_type(4)));
typedef float    f32x4 __attribute__((ext_vector_type(4)));

#define DIM   1024
#define NH    16
#define HD2   64
#define SEQ   2048
#define ROWS  4096   // b*n = 2*2048
#define QKVN  3072

__device__ __forceinline__ void async_copy16(void* lds, const void* gsrc) {
    __builtin_amdgcn_global_load_lds(
        (const __attribute__((address_space(1))) unsigned int*)gsrc,
        (__attribute__((address_space(3))) unsigned int*)lds, 16, 0, 0);
}

// ---------------- prologue: LN (blocks 0..4095) + transpose w_qkv + transpose w_out ----------------
__global__ __launch_bounds__(256) void prologue_kernel(
    const float* __restrict__ x, const float* __restrict__ gamma,
    const float* __restrict__ beta, _Float16* __restrict__ xn,
    const float* __restrict__ w_qkv, _Float16* __restrict__ wqkvT,
    const float* __restrict__ w_out, _Float16* __restrict__ woutT) {
    __shared__ float smem[32 * 33];
    const int bid = blockIdx.x;
    const int t = threadIdx.x;
    if (bid < ROWS) {
        const int row = bid;
        const float4 v = reinterpret_cast<const float4*>(x + (size_t)row * DIM)[t];
        float s1 = v.x + v.y + v.z + v.w;
        float s2 = v.x * v.x + v.y * v.y + v.z * v.z + v.w * v.w;
        for (int off = 32; off; off >>= 1) {
            s1 += __shfl_down(s1, off);
            s2 += __shfl_down(s2, off);
        }
        const int wv = t >> 6, lane = t & 63;
        if (lane == 0) { smem[wv * 2] = s1; smem[wv * 2 + 1] = s2; }
        __syncthreads();
        s1 = smem[0] + smem[2] + smem[4] + smem[6];
        s2 = smem[1] + smem[3] + smem[5] + smem[7];
        const float mu = s1 * (1.0f / DIM);
        const float var = s2 * (1.0f / DIM) - mu * mu;
        const float rstd = rsqrtf(var + 1e-5f);
        const float4 g = reinterpret_cast<const float4*>(gamma)[t];
        const float4 bb = reinterpret_cast<const float4*>(beta)[t];
        f16x4 o;
        o[0] = (_Float16)((v.x - mu) * rstd * g.x + bb.x);
        o[1] = (_Float16)((v.y - mu) * rstd * g.y + bb.y);
        o[2] = (_Float16)((v.z - mu) * rstd * g.z + bb.z);
        o[3] = (_Float16)((v.w - mu) * rstd * g.w + bb.w);
        reinterpret_cast<f16x4*>(xn + (size_t)row * DIM)[t] = o;
        return;
    }
    const float* in;
    _Float16* out;
    int C, bx, by;
    if (bid < ROWS + (QKVN / 32) * (DIM / 32)) {
        const int q = bid - ROWS;
        in = w_qkv; out = wqkvT; C = QKVN;
        bx = q % (QKVN / 32); by = q / (QKVN / 32);
    } else {
        const int q = bid - ROWS - (QKVN / 32) * (DIM / 32);
        in = w_out; out = woutT; C = DIM;
        bx = q % (DIM / 32); by = q / (DIM / 32);
    }
    const int R = DIM;
    const int c0 = bx * 32, r0 = by * 32;
    const int tx = t & 31, ty = t >> 5;
    float (*tile)[33] = reinterpret_cast<float(*)[33]>(smem);
#pragma unroll
    for (int i = 0; i < 4; i++)
        tile[ty + i * 8][tx] = in[(size_t)(r0 + ty + i * 8) * C + c0 + tx];
    __syncthreads();
#pragma unroll
    for (int i = 0; i < 4; i++)
        out[(size_t)(c0 + ty + i * 8) * R + r0 + tx] = (_Float16)tile[tx][ty + i * 8];
}

// ------------- QKV GEMM: xn (4096x1024) * wqkvT (3072x1024), 2-phase dbuf, XCD-chunked -------------
__global__ __launch_bounds__(256) void gemm_qkv_kernel(
    const _Float16* __restrict__ A, const _Float16* __restrict__ Bt,
    _Float16* __restrict__ qk, _Float16* __restrict__ vT, int K) {
    __shared__ _Float16 Al[2][128 * 32];
    __shared__ _Float16 Bl[2][128 * 32];
    const int t = threadIdx.x, wv = t >> 6, lane = t & 63;
    const int lg = lane >> 4, lr = lane & 15;
    const int wr = wv >> 1, wc = wv & 1;
    const int id = blockIdx.x;
    const int nid = (id & 7) * 96 + (id >> 3);       // 768 = 8 x 96
    const int bx = nid / 32, by = nid % 32;
    const int m0 = by * 128, n0 = bx * 128;

    f32x4 acc[4][4] = {};

    const int srow = t >> 2, sk = (t & 3) * 8;
    const _Float16* Ag0 = A + (size_t)(m0 + srow) * K + sk;
    const _Float16* Bg0 = Bt + (size_t)(n0 + srow) * K + sk;

    auto STAGE = [&](int buf, int k0) {
        _Float16* Alw = &Al[buf][wv * 512];
        _Float16* Blw = &Bl[buf][wv * 512];
        async_copy16(Alw,        Ag0 + k0);
        async_copy16(Alw + 2048, Ag0 + (size_t)64 * K + k0);
        async_copy16(Blw,        Bg0 + k0);
        async_copy16(Blw + 2048, Bg0 + (size_t)64 * K + k0);
    };

    STAGE(0, 0);
    asm volatile("s_waitcnt vmcnt(0)" ::: "memory");
    __builtin_amdgcn_s_barrier();
    int cur = 0;
    for (int k0 = 0; k0 < K; k0 += 32) {
        if (k0 + 32 < K) STAGE(cur ^ 1, k0 + 32);
        const _Float16* Ab = &Al[cur][0];
        const _Float16* Bb = &Bl[cur][0];
        f16x8 af[4], bfr[4];
#pragma unroll
        for (int m = 0; m < 4; m++)
            af[m] = *reinterpret_cast<const f16x8*>(&Ab[(wr * 64 + m * 16 + lr) * 32 + lg * 8]);
#pragma unroll
        for (int n = 0; n < 4; n++)
            bfr[n] = *reinterpret_cast<const f16x8*>(&Bb[(wc * 64 + n * 16 + lr) * 32 + lg * 8]);
#pragma unroll
        for (int m = 0; m < 4; m++)
#pragma unroll
            for (int n = 0; n < 4; n++)
                acc[m][n] = __builtin_amdgcn_mfma_f32_16x16x32_f16(af[m], bfr[n], acc[m][n], 0, 0, 0);
        asm volatile("s_waitcnt vmcnt(0)" ::: "memory");
        __builtin_amdgcn_s_barrier();
        cur ^= 1;
    }

    if (n0 < 2 * DIM) {
#pragma unroll
        for (int m = 0; m < 4; m++) {
            const int row = m0 + wr * 64 + m * 16 + lg * 4;
#pragma unroll
            for (int n = 0; n < 4; n++) {
                const int col = n0 + wc * 64 + n * 16 + lr;
#pragma unroll
                for (int jj = 0; jj < 4; jj++)
                    qk[(size_t)(row + jj) * 2048 + col] = (_Float16)acc[m][n][jj];
            }
        }
    } else {
#pragma unroll
        for (int m = 0; m < 4; m++) {
            const int row = m0 + wr * 64 + m * 16 + lg * 4;
            const int b = row >> 11, nn = row & 2047;
#pragma unroll
            for (int n = 0; n < 4; n++) {
                const int vcol = n0 + wc * 64 + n * 16 + lr - 2 * DIM;
                f16x4 pk;
#pragma unroll
                for (int jj = 0; jj < 4; jj++) pk[jj] = (_Float16)acc[m][n][jj];
                *reinterpret_cast<f16x4*>(&vT[(size_t)(b * 1024 + vcol) * SEQ + nn]) = pk;
            }
        }
    }
}

// ------------- out-proj GEMM: attn (4096x1024) * woutT (1024x1024) + bias -> f32 -------------
__global__ __launch_bounds__(256) void gemm_out_kernel(
    const _Float16* __restrict__ A, const _Float16* __restrict__ Bt,
    float* __restrict__ C, const float* __restrict__ bias, int N, int K) {
    __shared__ _Float16 Al[2][128 * 32];
    __shared__ _Float16 Bl[2][64 * 32];
    const int t = threadIdx.x, wv = t >> 6, lane = t & 63;
    const int lg = lane >> 4, lr = lane & 15;
    const int wr = wv >> 1, wc = wv & 1;
    const int id = blockIdx.x;
    const int nid = (id & 7) * 64 + (id >> 3);       // 512 = 8 x 64
    const int bx = nid / 32, by = nid % 32;
    const int m0 = by * 128, n0 = bx * 64;

    f32x4 acc[4][2] = {};

    const int srow = t >> 2, sk = (t & 3) * 8;
    const _Float16* Ag0 = A + (size_t)(m0 + srow) * K + sk;
    const _Float16* Bg0 = Bt + (size_t)(n0 + srow) * K + sk;

    auto STAGE = [&](int buf, int k0) {
        _Float16* Alw = &Al[buf][wv * 512];
        _Float16* Blw = &Bl[buf][wv * 512];
        async_copy16(Alw,        Ag0 + k0);
        async_copy16(Alw + 2048, Ag0 + (size_t)64 * K + k0);
        async_copy16(Blw,        Bg0 + k0);
    };

    STAGE(0, 0);
    asm volatile("s_waitcnt vmcnt(0)" ::: "memory");
    __builtin_amdgcn_s_barrier();
    int cur = 0;
    for (int k0 = 0; k0 < K; k0 += 32) {
        if (k0 + 32 < K) STAGE(cur ^ 1, k0 + 32);
        const _Float16* Ab = &Al[cur][0];
        const _Float16* Bb = &Bl[cur][0];
        f16x8 af[4], bfr[2];
#pragma unroll
        for (int m = 0; m < 4; m++)
            af[m] = *reinterpret_cast<const f16x8*>(&Ab[(wr * 64 + m * 16 + lr) * 32 + lg * 8]);
#pragma unroll
        for (int n = 0; n < 2; n++)
            bfr[n] = *reinterpret_cast<const f16x8*>(&Bb[(wc * 32 + n * 16 + lr) * 32 + lg * 8]);
#pragma unroll
        for (int m = 0; m < 4; m++)
#pragma unroll
            for (int n = 0; n < 2; n++)
                acc[m][n] = __builtin_amdgcn_mfma_f32_16x16x32_f16(af[m], bfr[n], acc[m][n], 0, 0, 0);
        asm volatile("s_waitcnt vmcnt(0)" ::: "memory");
        __builtin_amdgcn_s_barrier();
        cur ^= 1;
    }

#pragma unroll
    for (int m = 0; m < 4; m++) {
        const int row = m0 + wr * 64 + m * 16 + lg * 4;
#pragma unroll
        for (int n = 0; n < 2; n++) {
            const int col = n0 + wc * 32 + n * 16 + lr;
            const float bo = bias[col];
#pragma unroll
            for (int jj = 0; jj < 4; jj++)
                C[(size_t)(row + jj) * N + col] = acc[m][n][jj] + bo;
        }
    }
}

// ------------- flash attention: QBLK=128, lane-local P, dbuf K/V, pad-76 (conflict-free) -------------
// grid 512 blocks (XCD-swizzled), 4 waves; wave owns 32 q rows (2 sets of 16); KV tile 64.
__global__ __launch_bounds__(256, 2) void attn_fa_kernel(
    const _Float16* __restrict__ qk, const _Float16* __restrict__ vT,
    _Float16* __restrict__ attn) {
    const int id = blockIdx.x;
    const int nid = (id & 7) * 64 + (id >> 3);     // bijective: 512 = 8 XCD x 64
    const int bh = nid >> 4, b = bh >> 4, h = bh & 15;
    const int q0 = (nid & 15) * 128;
    const int t = threadIdx.x, wv = t >> 6, lane = t & 63;
    const int lg = lane >> 4, lr = lane & 15;

    __shared__ _Float16 Kl[2][64][76];    // K tile [key][d], pad 76 (stride 152B: conflict-free)
    __shared__ _Float16 Vt[2][64][76];    // V^T tile [d][key]

    // Q fragments (B operand: col q=lr, k=d), q-set qs covers q = q0+wv*32+qs*16+lr
    const _Float16* qb = qk + (size_t)(b * SEQ + q0 + wv * 32 + lr) * 2048 + h * HD2;
    f16x8 qf[2][2];
    qf[0][0] = *reinterpret_cast<const f16x8*>(qb + lg * 8);
    qf[0][1] = *reinterpret_cast<const f16x8*>(qb + 32 + lg * 8);
    qf[1][0] = *reinterpret_cast<const f16x8*>(qb + (size_t)16 * 2048 + lg * 8);
    qf[1][1] = *reinterpret_cast<const f16x8*>(qb + (size_t)16 * 2048 + 32 + lg * 8);
#pragma unroll
    for (int qs = 0; qs < 2; qs++) {
        qf[qs][0] = qf[qs][0] * (_Float16)0.125f;
        qf[qs][1] = qf[qs][1] * (_Float16)0.125f;
    }

    f32x4 o[2][4] = {};                    // O^T per q-set: d = dn*16+lg*4+jj, q = lr
    float mrun[2] = {-INFINITY, -INFINITY}, lrun[2] = {0.f, 0.f};

    const int sr = t >> 3, sc = (t & 7) * 8;
    const _Float16* kbase = qk + (size_t)(b * SEQ + sr) * 2048 + DIM + h * HD2 + sc;
    const _Float16* vbase = vT + (size_t)(bh * HD2 + sr) * SEQ + sc;

    // prologue: tile 0 -> buf 0; prefetch tile 1 into regs
    f16x8 rk0 = *reinterpret_cast<const f16x8*>(kbase);
    f16x8 rk1 = *reinterpret_cast<const f16x8*>(kbase + (size_t)32 * 2048);
    f16x8 rv0 = *reinterpret_cast<const f16x8*>(vbase);
    f16x8 rv1 = *reinterpret_cast<const f16x8*>(vbase + (size_t)32 * SEQ);
    *reinterpret_cast<f16x8*>(&Kl[0][sr][sc])      = rk0;
    *reinterpret_cast<f16x8*>(&Kl[0][sr + 32][sc]) = rk1;
    *reinterpret_cast<f16x8*>(&Vt[0][sr][sc])      = rv0;
    *reinterpret_cast<f16x8*>(&Vt[0][sr + 32][sc]) = rv1;
    rk0 = *reinterpret_cast<const f16x8*>(kbase + (size_t)64 * 2048);
    rk1 = *reinterpret_cast<const f16x8*>(kbase + (size_t)96 * 2048);
    rv0 = *reinterpret_cast<const f16x8*>(vbase + 64);
    rv1 = *reinterpret_cast<const f16x8*>(vbase + (size_t)32 * SEQ + 64);
    asm volatile("s_waitcnt lgkmcnt(0)" ::: "memory");
    __builtin_amdgcn_s_barrier();

    int p = 0;
    for (int kv0 = 0; kv0 < SEQ; kv0 += 64, p ^= 1) {
        if (kv0 + 64 < SEQ) {
            *reinterpret_cast<f16x8*>(&Kl[p ^ 1][sr][sc])      = rk0;
            *reinterpret_cast<f16x8*>(&Kl[p ^ 1][sr + 32][sc]) = rk1;
            *reinterpret_cast<f16x8*>(&Vt[p ^ 1][sr][sc])      = rv0;
            *reinterpret_cast<f16x8*>(&Vt[p ^ 1][sr + 32][sc]) = rv1;
            if (kv0 + 128 < SEQ) {
                const _Float16* kp = kbase + (size_t)(kv0 + 128) * 2048;
                const _Float16* vp = vbase + (kv0 + 128);
                rk0 = *reinterpret_cast<const f16x8*>(kp);
                rk1 = *reinterpret_cast<const f16x8*>(kp + (size_t)32 * 2048);
                rv0 = *reinterpret_cast<const f16x8*>(vp);
                rv1 = *reinterpret_cast<const f16x8*>(vp + (size_t)32 * SEQ);
            }
        }

        // ---- S^T = K Q^T : lane holds keys {n*16+lg*4+jj} for q=lr, per q-set
        f32x4 s[2][4];
#pragma unroll
        for (int n = 0; n < 4; n++) {
            f16x8 kf0 = *reinterpret_cast<const f16x8*>(&Kl[p][n * 16 + lr][lg * 8]);
            f16x8 kf1 = *reinterpret_cast<const f16x8*>(&Kl[p][n * 16 + lr][32 + lg * 8]);
            __builtin_amdgcn_s_setprio(1);
#pragma unroll
            for (int qs = 0; qs < 2; qs++) {
                f32x4 z = {0.f, 0.f, 0.f, 0.f};
                z = __builtin_amdgcn_mfma_f32_16x16x32_f16(kf0, qf[qs][0], z, 0, 0, 0);
                z = __builtin_amdgcn_mfma_f32_16x16x32_f16(kf1, qf[qs][1], z, 0, 0, 0);
                s[qs][n] = z;
            }
            __builtin_amdgcn_s_setprio(0);
        }

        // ---- online softmax (defer-max) + lane-local P fragments
        f16x8 pa[2][2];
#pragma unroll
        for (int qs = 0; qs < 2; qs++) {
            // vectorized max tree (element-wise f32x4, then horizontal)
            f32x4 m4a = s[qs][0], m4b = s[qs][2];
#pragma unroll
            for (int jj = 0; jj < 4; jj++) {
                m4a[jj] = fmaxf(m4a[jj], s[qs][1][jj]);
                m4b[jj] = fmaxf(m4b[jj], s[qs][3][jj]);
            }
            float m1 = fmaxf(fmaxf(fmaxf(m4a[0], m4b[0]), fmaxf(m4a[1], m4b[1])),
                             fmaxf(fmaxf(m4a[2], m4b[2]), fmaxf(m4a[3], m4b[3])));
            m1 = fmaxf(m1, __shfl_xor(m1, 16));
            m1 = fmaxf(m1, __shfl_xor(m1, 32));
            if (!__all(m1 - mrun[qs] <= 8.f)) {
                const float mnew = fmaxf(mrun[qs], m1);
                const float corr = __expf(mrun[qs] - mnew);
                mrun[qs] = mnew;
                lrun[qs] *= corr;
#pragma unroll
                for (int dn = 0; dn < 4; dn++) o[qs][dn] *= corr;
            }
#pragma unroll
            for (int n = 0; n < 4; n++)
#pragma unroll
                for (int jj = 0; jj < 4; jj++)
                    s[qs][n][jj] = __expf(s[qs][n][jj] - mrun[qs]);
            // vectorized sum tree
            f32x4 a4 = s[qs][0] + s[qs][1];
            f32x4 b4 = s[qs][2] + s[qs][3];
            a4 = a4 + b4;
            float rsum = (a4[0] + a4[1]) + (a4[2] + a4[3]);
            rsum += __shfl_xor(rsum, 16);
            rsum += __shfl_xor(rsum, 32);
            lrun[qs] += rsum;
            // pack: mfma m consumes key chunks {2m, 2m+1}; slot j -> key (2m+(j>>2))*16+lg*4+(j&3)
#pragma unroll
            for (int m = 0; m < 2; m++) {
                f16x8 pv;
#pragma unroll
                for (int jj = 0; jj < 4; jj++) {
                    pv[jj]     = (_Float16)s[qs][2 * m][jj];
                    pv[4 + jj] = (_Float16)s[qs][2 * m + 1][jj];
                }
                pa[qs][m] = pv;
            }
        }

        // ---- O^T += V^T P with the SAME key permutation on V (2x b64 per frag)
#pragma unroll
        for (int dn = 0; dn < 4; dn++) {
            const _Float16* vr = &Vt[p][dn * 16 + lr][0];
            f16x4 va0 = *reinterpret_cast<const f16x4*>(vr + lg * 4);         // chunk 0
            f16x4 va1 = *reinterpret_cast<const f16x4*>(vr + 16 + lg * 4);    // chunk 1
            f16x4 vb0 = *reinterpret_cast<const f16x4*>(vr + 32 + lg * 4);    // chunk 2
            f16x4 vb1 = *reinterpret_cast<const f16x4*>(vr + 48 + lg * 4);    // chunk 3
            f16x8 vf0, vf1;
#pragma unroll
            for (int j = 0; j < 4; j++) {
                vf0[j] = va0[j]; vf0[4 + j] = va1[j];
                vf1[j] = vb0[j]; vf1[4 + j] = vb1[j];
            }
            __builtin_amdgcn_s_setprio(1);
#pragma unroll
            for (int qs = 0; qs < 2; qs++) {
                o[qs][dn] = __builtin_amdgcn_mfma_f32_16x16x32_f16(vf0, pa[qs][0], o[qs][dn], 0, 0, 0);
                o[qs][dn] = __builtin_amdgcn_mfma_f32_16x16x32_f16(vf1, pa[qs][1], o[qs][dn], 0, 0, 0);
            }
            __builtin_amdgcn_s_setprio(0);
        }
        asm volatile("s_waitcnt lgkmcnt(0)" ::: "memory");   // my LDS reads landed
        __builtin_amdgcn_s_barrier();
    }

    // epilogue: O[q][d] = O^T/l ; q = q0+wv*32+qs*16+lr, d = dn*16+lg*4+jj
#pragma unroll
    for (int qs = 0; qs < 2; qs++) {
        const float inv = 1.0f / lrun[qs];
        const size_t orow = (size_t)(b * SEQ + q0 + wv * 32 + qs * 16 + lr);
#pragma unroll
        for (int dn = 0; dn < 4; dn++) {
            f16x4 pk;
#pragma unroll
            for (int jj = 0; jj < 4; jj++) pk[jj] = (_Float16)(o[qs][dn][jj] * inv);
            *reinterpret_cast<f16x4*>(&attn[orow * DIM + h * HD2 + dn * 16 + lg * 4]) = pk;
        }
    }
}

extern "C" void kernel_launch(void* const* d_in, const int* in_sizes, int n_in,
                              void* d_out, int out_size, void* d_ws, size_t ws_size,
                              hipStream_t stream) {
    const float* x     = (const float*)d_in[0];
    const float* gamma = (const float*)d_in[1];
    const float* beta  = (const float*)d_in[2];
    const float* w_qkv = (const float*)d_in[3];
    const float* w_out = (const float*)d_in[4];
    const float* b_out = (const float*)d_in[5];
    float* out = (float*)d_out;

    _Float16* ws    = (_Float16*)d_ws;
    _Float16* xn    = ws;                                  // 4096*1024
    _Float16* wqkvT = xn + (size_t)ROWS * DIM;             // 3072*1024
    _Float16* woutT = wqkvT + (size_t)QKVN * DIM;          // 1024*1024
    _Float16* qk    = woutT + (size_t)DIM * DIM;           // 4096*2048
    _Float16* vT    = qk + (size_t)ROWS * 2048;            // (32*64)*2048
    _Float16* attnb = xn;                                  // reuse xn region

    const int pro_blocks = ROWS + (QKVN / 32) * (DIM / 32) + (DIM / 32) * (DIM / 32);
    prologue_kernel<<<pro_blocks, 256, 0, stream>>>(x, gamma, beta, xn, w_qkv, wqkvT, w_out, woutT);
    gemm_qkv_kernel<<<768, 256, 0, stream>>>(xn, wqkvT, qk, vT, DIM);
    attn_fa_kernel<<<512, 256, 0, stream>>>(qk, vT, attnb);
    gemm_out_kernel<<<512, 256, 0, stream>>>(attnb, woutT, out, b_out, DIM, DIM);
}

// Round 10
// 197.244 us; speedup vs baseline: 1.0590x; 1.0181x over previous
//
#include <hip/hip_runtime.h>
#include <hip/hip_bf16.h>

// Fused: [LN + weight transposes] -> QKV proj (V transposed) -> attention -> out proj + bias.

typedef _Float16 f16x8 __attribute__((ext_vector_type(8)));
typedef _Float16 f16x4 __attribute__((ext_vector_type(4)));
typedef float    f32x4 __attribute__((ext_vector_type(4)));

#define DIM   1024
#define NH    16
#define HD2   64
#define SEQ   2048
#define ROWS  4096   // b*n = 2*2048
#define QKVN  3072

__device__ __forceinline__ void async_copy16(void* lds, const void* gsrc) {
    __builtin_amdgcn_global_load_lds(
        (const __attribute__((address_space(1))) unsigned int*)gsrc,
        (__attribute__((address_space(3))) unsigned int*)lds, 16, 0, 0);
}

// ---------------- prologue: LN (blocks 0..4095) + transpose w_qkv + transpose w_out ----------------
__global__ __launch_bounds__(256) void prologue_kernel(
    const float* __restrict__ x, const float* __restrict__ gamma,
    const float* __restrict__ beta, _Float16* __restrict__ xn,
    const float* __restrict__ w_qkv, _Float16* __restrict__ wqkvT,
    const float* __restrict__ w_out, _Float16* __restrict__ woutT) {
    __shared__ float smem[32 * 33];
    const int bid = blockIdx.x;
    const int t = threadIdx.x;
    if (bid < ROWS) {
        const int row = bid;
        const float4 v = reinterpret_cast<const float4*>(x + (size_t)row * DIM)[t];
        float s1 = v.x + v.y + v.z + v.w;
        float s2 = v.x * v.x + v.y * v.y + v.z * v.z + v.w * v.w;
        for (int off = 32; off; off >>= 1) {
            s1 += __shfl_down(s1, off);
            s2 += __shfl_down(s2, off);
        }
        const int wv = t >> 6, lane = t & 63;
        if (lane == 0) { smem[wv * 2] = s1; smem[wv * 2 + 1] = s2; }
        __syncthreads();
        s1 = smem[0] + smem[2] + smem[4] + smem[6];
        s2 = smem[1] + smem[3] + smem[5] + smem[7];
        const float mu = s1 * (1.0f / DIM);
        const float var = s2 * (1.0f / DIM) - mu * mu;
        const float rstd = rsqrtf(var + 1e-5f);
        const float4 g = reinterpret_cast<const float4*>(gamma)[t];
        const float4 bb = reinterpret_cast<const float4*>(beta)[t];
        f16x4 o;
        o[0] = (_Float16)((v.x - mu) * rstd * g.x + bb.x);
        o[1] = (_Float16)((v.y - mu) * rstd * g.y + bb.y);
        o[2] = (_Float16)((v.z - mu) * rstd * g.z + bb.z);
        o[3] = (_Float16)((v.w - mu) * rstd * g.w + bb.w);
        reinterpret_cast<f16x4*>(xn + (size_t)row * DIM)[t] = o;
        return;
    }
    const float* in;
    _Float16* out;
    int C, bx, by;
    if (bid < ROWS + (QKVN / 32) * (DIM / 32)) {
        const int q = bid - ROWS;
        in = w_qkv; out = wqkvT; C = QKVN;
        bx = q % (QKVN / 32); by = q / (QKVN / 32);
    } else {
        const int q = bid - ROWS - (QKVN / 32) * (DIM / 32);
        in = w_out; out = woutT; C = DIM;
        bx = q % (DIM / 32); by = q / (DIM / 32);
    }
    const int R = DIM;
    const int c0 = bx * 32, r0 = by * 32;
    const int tx = t & 31, ty = t >> 5;
    float (*tile)[33] = reinterpret_cast<float(*)[33]>(smem);
#pragma unroll
    for (int i = 0; i < 4; i++)
        tile[ty + i * 8][tx] = in[(size_t)(r0 + ty + i * 8) * C + c0 + tx];
    __syncthreads();
#pragma unroll
    for (int i = 0; i < 4; i++)
        out[(size_t)(c0 + ty + i * 8) * R + r0 + tx] = (_Float16)tile[tx][ty + i * 8];
}

// ------------- QKV GEMM: xn (4096x1024) * wqkvT (3072x1024), 2-phase dbuf, XCD-chunked -------------
__global__ __launch_bounds__(256) void gemm_qkv_kernel(
    const _Float16* __restrict__ A, const _Float16* __restrict__ Bt,
    _Float16* __restrict__ qk, _Float16* __restrict__ vT, int K) {
    __shared__ _Float16 Al[2][128 * 32];
    __shared__ _Float16 Bl[2][128 * 32];
    const int t = threadIdx.x, wv = t >> 6, lane = t & 63;
    const int lg = lane >> 4, lr = lane & 15;
    const int wr = wv >> 1, wc = wv & 1;
    const int id = blockIdx.x;
    const int nid = (id & 7) * 96 + (id >> 3);       // 768 = 8 x 96
    const int bx = nid / 32, by = nid % 32;
    const int m0 = by * 128, n0 = bx * 128;

    f32x4 acc[4][4] = {};

    const int srow = t >> 2, sk = (t & 3) * 8;
    const _Float16* Ag0 = A + (size_t)(m0 + srow) * K + sk;
    const _Float16* Bg0 = Bt + (size_t)(n0 + srow) * K + sk;

    auto STAGE = [&](int buf, int k0) {
        _Float16* Alw = &Al[buf][wv * 512];
        _Float16* Blw = &Bl[buf][wv * 512];
        async_copy16(Alw,        Ag0 + k0);
        async_copy16(Alw + 2048, Ag0 + (size_t)64 * K + k0);
        async_copy16(Blw,        Bg0 + k0);
        async_copy16(Blw + 2048, Bg0 + (size_t)64 * K + k0);
    };

    STAGE(0, 0);
    asm volatile("s_waitcnt vmcnt(0)" ::: "memory");
    __builtin_amdgcn_s_barrier();
    int cur = 0;
    for (int k0 = 0; k0 < K; k0 += 32) {
        if (k0 + 32 < K) STAGE(cur ^ 1, k0 + 32);
        const _Float16* Ab = &Al[cur][0];
        const _Float16* Bb = &Bl[cur][0];
        f16x8 af[4], bfr[4];
#pragma unroll
        for (int m = 0; m < 4; m++)
            af[m] = *reinterpret_cast<const f16x8*>(&Ab[(wr * 64 + m * 16 + lr) * 32 + lg * 8]);
#pragma unroll
        for (int n = 0; n < 4; n++)
            bfr[n] = *reinterpret_cast<const f16x8*>(&Bb[(wc * 64 + n * 16 + lr) * 32 + lg * 8]);
#pragma unroll
        for (int m = 0; m < 4; m++)
#pragma unroll
            for (int n = 0; n < 4; n++)
                acc[m][n] = __builtin_amdgcn_mfma_f32_16x16x32_f16(af[m], bfr[n], acc[m][n], 0, 0, 0);
        asm volatile("s_waitcnt vmcnt(0)" ::: "memory");
        __builtin_amdgcn_s_barrier();
        cur ^= 1;
    }

    if (n0 < 2 * DIM) {
#pragma unroll
        for (int m = 0; m < 4; m++) {
            const int row = m0 + wr * 64 + m * 16 + lg * 4;
#pragma unroll
            for (int n = 0; n < 4; n++) {
                const int col = n0 + wc * 64 + n * 16 + lr;
#pragma unroll
                for (int jj = 0; jj < 4; jj++)
                    qk[(size_t)(row + jj) * 2048 + col] = (_Float16)acc[m][n][jj];
            }
        }
    } else {
#pragma unroll
        for (int m = 0; m < 4; m++) {
            const int row = m0 + wr * 64 + m * 16 + lg * 4;
            const int b = row >> 11, nn = row & 2047;
#pragma unroll
            for (int n = 0; n < 4; n++) {
                const int vcol = n0 + wc * 64 + n * 16 + lr - 2 * DIM;
                f16x4 pk;
#pragma unroll
                for (int jj = 0; jj < 4; jj++) pk[jj] = (_Float16)acc[m][n][jj];
                *reinterpret_cast<f16x4*>(&vT[(size_t)(b * 1024 + vcol) * SEQ + nn]) = pk;
            }
        }
    }
}

// ------------- out-proj GEMM: attn (4096x1024) * woutT (1024x1024) + bias -> f32 -------------
__global__ __launch_bounds__(256) void gemm_out_kernel(
    const _Float16* __restrict__ A, const _Float16* __restrict__ Bt,
    float* __restrict__ C, const float* __restrict__ bias, int N, int K) {
    __shared__ _Float16 Al[2][128 * 32];
    __shared__ _Float16 Bl[2][64 * 32];
    const int t = threadIdx.x, wv = t >> 6, lane = t & 63;
    const int lg = lane >> 4, lr = lane & 15;
    const int wr = wv >> 1, wc = wv & 1;
    const int id = blockIdx.x;
    const int nid = (id & 7) * 64 + (id >> 3);       // 512 = 8 x 64
    const int bx = nid / 32, by = nid % 32;
    const int m0 = by * 128, n0 = bx * 64;

    f32x4 acc[4][2] = {};

    const int srow = t >> 2, sk = (t & 3) * 8;
    const _Float16* Ag0 = A + (size_t)(m0 + srow) * K + sk;
    const _Float16* Bg0 = Bt + (size_t)(n0 + srow) * K + sk;

    auto STAGE = [&](int buf, int k0) {
        _Float16* Alw = &Al[buf][wv * 512];
        _Float16* Blw = &Bl[buf][wv * 512];
        async_copy16(Alw,        Ag0 + k0);
        async_copy16(Alw + 2048, Ag0 + (size_t)64 * K + k0);
        async_copy16(Blw,        Bg0 + k0);
    };

    STAGE(0, 0);
    asm volatile("s_waitcnt vmcnt(0)" ::: "memory");
    __builtin_amdgcn_s_barrier();
    int cur = 0;
    for (int k0 = 0; k0 < K; k0 += 32) {
        if (k0 + 32 < K) STAGE(cur ^ 1, k0 + 32);
        const _Float16* Ab = &Al[cur][0];
        const _Float16* Bb = &Bl[cur][0];
        f16x8 af[4], bfr[2];
#pragma unroll
        for (int m = 0; m < 4; m++)
            af[m] = *reinterpret_cast<const f16x8*>(&Ab[(wr * 64 + m * 16 + lr) * 32 + lg * 8]);
#pragma unroll
        for (int n = 0; n < 2; n++)
            bfr[n] = *reinterpret_cast<const f16x8*>(&Bb[(wc * 32 + n * 16 + lr) * 32 + lg * 8]);
#pragma unroll
        for (int m = 0; m < 4; m++)
#pragma unroll
            for (int n = 0; n < 2; n++)
                acc[m][n] = __builtin_amdgcn_mfma_f32_16x16x32_f16(af[m], bfr[n], acc[m][n], 0, 0, 0);
        asm volatile("s_waitcnt vmcnt(0)" ::: "memory");
        __builtin_amdgcn_s_barrier();
        cur ^= 1;
    }

#pragma unroll
    for (int m = 0; m < 4; m++) {
        const int row = m0 + wr * 64 + m * 16 + lg * 4;
#pragma unroll
        for (int n = 0; n < 2; n++) {
            const int col = n0 + wc * 32 + n * 16 + lr;
            const float bo = bias[col];
#pragma unroll
            for (int jj = 0; jj < 4; jj++)
                C[(size_t)(row + jj) * N + col] = acc[m][n][jj] + bo;
        }
    }
}

// ------------- flash attention: QBLK=128, lane-local P, deferred-PV pipeline (T15) -------------
// grid 512 blocks (XCD-swizzled), 4 waves; wave owns 32 q rows (2 sets of 16); KV tile 64.
// Iter t: QK(t) -> PV(t-1) -> readV(t)->regs -> softmax(t). PV MFMA overlaps softmax VALU.
__global__ __launch_bounds__(256, 2) void attn_fa_kernel(
    const _Float16* __restrict__ qk, const _Float16* __restrict__ vT,
    _Float16* __restrict__ attn) {
    const int id = blockIdx.x;
    const int nid = (id & 7) * 64 + (id >> 3);     // bijective: 512 = 8 XCD x 64
    const int bh = nid >> 4, b = bh >> 4, h = bh & 15;
    const int q0 = (nid & 15) * 128;
    const int t = threadIdx.x, wv = t >> 6, lane = t & 63;
    const int lg = lane >> 4, lr = lane & 15;

    __shared__ _Float16 Kl[2][64][76];    // K tile [key][d], pad 76 (conflict-free)
    __shared__ _Float16 Vt[2][64][76];    // V^T tile [d][key]

    // Q fragments (B operand: col q=lr, k=d), q-set qs covers q = q0+wv*32+qs*16+lr
    const _Float16* qb = qk + (size_t)(b * SEQ + q0 + wv * 32 + lr) * 2048 + h * HD2;
    f16x8 qf[2][2];
    qf[0][0] = *reinterpret_cast<const f16x8*>(qb + lg * 8);
    qf[0][1] = *reinterpret_cast<const f16x8*>(qb + 32 + lg * 8);
    qf[1][0] = *reinterpret_cast<const f16x8*>(qb + (size_t)16 * 2048 + lg * 8);
    qf[1][1] = *reinterpret_cast<const f16x8*>(qb + (size_t)16 * 2048 + 32 + lg * 8);
#pragma unroll
    for (int qs = 0; qs < 2; qs++) {
        qf[qs][0] = qf[qs][0] * (_Float16)0.125f;
        qf[qs][1] = qf[qs][1] * (_Float16)0.125f;
    }

    f32x4 o[2][4] = {};                    // O^T per q-set: d = dn*16+lg*4+jj, q = lr
    float mrun[2] = {-INFINITY, -INFINITY}, lrun[2] = {0.f, 0.f};

    const int sr = t >> 3, sc = (t & 7) * 8;
    const _Float16* kbase = qk + (size_t)(b * SEQ + sr) * 2048 + DIM + h * HD2 + sc;
    const _Float16* vbase = vT + (size_t)(bh * HD2 + sr) * SEQ + sc;

    // global-prefetch registers (tile t+1 while in loop at tile t)
    f16x8 rk0, rk1, rv0, rv1;

    // ---- pipeline helpers
    f32x4 s[2][4];
    f16x8 vfr[4][2];      // V fragments of the "previous" tile (consumed by PV, then refilled)
    f16x8 pa[2][2];       // P fragments of the "previous" tile

    auto STAGEW = [&](int pb, int kv_next) {   // write regs(tile kv_next) -> buf pb, prefetch kv_next+64
        *reinterpret_cast<f16x8*>(&Kl[pb][sr][sc])      = rk0;
        *reinterpret_cast<f16x8*>(&Kl[pb][sr + 32][sc]) = rk1;
        *reinterpret_cast<f16x8*>(&Vt[pb][sr][sc])      = rv0;
        *reinterpret_cast<f16x8*>(&Vt[pb][sr + 32][sc]) = rv1;
        if (kv_next + 64 < SEQ) {
            const _Float16* kp = kbase + (size_t)(kv_next + 64) * 2048;
            const _Float16* vp = vbase + (kv_next + 64);
            rk0 = *reinterpret_cast<const f16x8*>(kp);
            rk1 = *reinterpret_cast<const f16x8*>(kp + (size_t)32 * 2048);
            rv0 = *reinterpret_cast<const f16x8*>(vp);
            rv1 = *reinterpret_cast<const f16x8*>(vp + (size_t)32 * SEQ);
        }
    };

    auto QK = [&](int p) {
#pragma unroll
        for (int n = 0; n < 4; n++) {
            f16x8 kf0 = *reinterpret_cast<const f16x8*>(&Kl[p][n * 16 + lr][lg * 8]);
            f16x8 kf1 = *reinterpret_cast<const f16x8*>(&Kl[p][n * 16 + lr][32 + lg * 8]);
            __builtin_amdgcn_s_setprio(1);
#pragma unroll
            for (int qs = 0; qs < 2; qs++) {
                f32x4 z = {0.f, 0.f, 0.f, 0.f};
                z = __builtin_amdgcn_mfma_f32_16x16x32_f16(kf0, qf[qs][0], z, 0, 0, 0);
                z = __builtin_amdgcn_mfma_f32_16x16x32_f16(kf1, qf[qs][1], z, 0, 0, 0);
                s[qs][n] = z;
            }
            __builtin_amdgcn_s_setprio(0);
        }
    };

    auto READV = [&](int p) {   // refill vfr with tile p's V fragments (permuted-key layout)
#pragma unroll
        for (int dn = 0; dn < 4; dn++) {
            const _Float16* vr = &Vt[p][dn * 16 + lr][0];
            f16x4 va0 = *reinterpret_cast<const f16x4*>(vr + lg * 4);
            f16x4 va1 = *reinterpret_cast<const f16x4*>(vr + 16 + lg * 4);
            f16x4 vb0 = *reinterpret_cast<const f16x4*>(vr + 32 + lg * 4);
            f16x4 vb1 = *reinterpret_cast<const f16x4*>(vr + 48 + lg * 4);
            f16x8 vf0, vf1;
#pragma unroll
            for (int j = 0; j < 4; j++) {
                vf0[j] = va0[j]; vf0[4 + j] = va1[j];
                vf1[j] = vb0[j]; vf1[4 + j] = vb1[j];
            }
            vfr[dn][0] = vf0; vfr[dn][1] = vf1;
        }
    };

    auto PV = [&]() {   // O += V~(prev) P~(prev)
#pragma unroll
        for (int dn = 0; dn < 4; dn++) {
            __builtin_amdgcn_s_setprio(1);
#pragma unroll
            for (int qs = 0; qs < 2; qs++) {
                o[qs][dn] = __builtin_amdgcn_mfma_f32_16x16x32_f16(vfr[dn][0], pa[qs][0], o[qs][dn], 0, 0, 0);
                o[qs][dn] = __builtin_amdgcn_mfma_f32_16x16x32_f16(vfr[dn][1], pa[qs][1], o[qs][dn], 0, 0, 0);
            }
            __builtin_amdgcn_s_setprio(0);
        }
    };

    auto SOFTMAX = [&]() {   // s -> pa, updates mrun/lrun, rescales o (defer-max)
#pragma unroll
        for (int qs = 0; qs < 2; qs++) {
            f32x4 m4a = s[qs][0], m4b = s[qs][2];
#pragma unroll
            for (int jj = 0; jj < 4; jj++) {
                m4a[jj] = fmaxf(m4a[jj], s[qs][1][jj]);
                m4b[jj] = fmaxf(m4b[jj], s[qs][3][jj]);
            }
            float m1 = fmaxf(fmaxf(fmaxf(m4a[0], m4b[0]), fmaxf(m4a[1], m4b[1])),
                             fmaxf(fmaxf(m4a[2], m4b[2]), fmaxf(m4a[3], m4b[3])));
            m1 = fmaxf(m1, __shfl_xor(m1, 16));
            m1 = fmaxf(m1, __shfl_xor(m1, 32));
            if (!__all(m1 - mrun[qs] <= 8.f)) {
                const float mnew = fmaxf(mrun[qs], m1);
                const float corr = __expf(mrun[qs] - mnew);
                mrun[qs] = mnew;
                lrun[qs] *= corr;
#pragma unroll
                for (int dn = 0; dn < 4; dn++) o[qs][dn] *= corr;
            }
#pragma unroll
            for (int n = 0; n < 4; n++)
#pragma unroll
                for (int jj = 0; jj < 4; jj++)
                    s[qs][n][jj] = __expf(s[qs][n][jj] - mrun[qs]);
            f32x4 a4 = (s[qs][0] + s[qs][1]) + (s[qs][2] + s[qs][3]);
            float rsum = (a4[0] + a4[1]) + (a4[2] + a4[3]);
            rsum += __shfl_xor(rsum, 16);
            rsum += __shfl_xor(rsum, 32);
            lrun[qs] += rsum;
#pragma unroll
            for (int m = 0; m < 2; m++) {
                f16x8 pv;
#pragma unroll
                for (int jj = 0; jj < 4; jj++) {
                    pv[jj]     = (_Float16)s[qs][2 * m][jj];
                    pv[4 + jj] = (_Float16)s[qs][2 * m + 1][jj];
                }
                pa[qs][m] = pv;
            }
        }
    };

    // ---- prologue: tile 0 -> buf 0 via regs; prefetch tile 1
    rk0 = *reinterpret_cast<const f16x8*>(kbase);
    rk1 = *reinterpret_cast<const f16x8*>(kbase + (size_t)32 * 2048);
    rv0 = *reinterpret_cast<const f16x8*>(vbase);
    rv1 = *reinterpret_cast<const f16x8*>(vbase + (size_t)32 * SEQ);
    *reinterpret_cast<f16x8*>(&Kl[0][sr][sc])      = rk0;
    *reinterpret_cast<f16x8*>(&Kl[0][sr + 32][sc]) = rk1;
    *reinterpret_cast<f16x8*>(&Vt[0][sr][sc])      = rv0;
    *reinterpret_cast<f16x8*>(&Vt[0][sr + 32][sc]) = rv1;
    {
        const _Float16* kp = kbase + (size_t)64 * 2048;
        const _Float16* vp = vbase + 64;
        rk0 = *reinterpret_cast<const f16x8*>(kp);
        rk1 = *reinterpret_cast<const f16x8*>(kp + (size_t)32 * 2048);
        rv0 = *reinterpret_cast<const f16x8*>(vp);
        rv1 = *reinterpret_cast<const f16x8*>(vp + (size_t)32 * SEQ);
    }
    asm volatile("s_waitcnt lgkmcnt(0)" ::: "memory");
    __builtin_amdgcn_s_barrier();

    // ---- peeled tile 0 (p=0): QK + readV + softmax (no PV yet)
    STAGEW(1, 64);
    QK(0);
    READV(0);
    SOFTMAX();
    asm volatile("s_waitcnt lgkmcnt(0)" ::: "memory");
    __builtin_amdgcn_s_barrier();

    // ---- main loop: tiles 1..31
    int p = 1;
    for (int kv0 = 64; kv0 < SEQ; kv0 += 64, p ^= 1) {
        if (kv0 + 64 < SEQ) STAGEW(p ^ 1, kv0 + 64);
        QK(p);        // S(t) from Kl[p]
        PV();         // O += V(t-1) P(t-1)  [MFMA, overlaps softmax below via pipe diversity]
        READV(p);     // refill vfr with V(t)
        SOFTMAX();    // s(t) -> pa(t), rescale o (holds tiles <= t-1: correct)
        asm volatile("s_waitcnt lgkmcnt(0)" ::: "memory");
        __builtin_amdgcn_s_barrier();
    }
    PV();             // final tile's PV

    // epilogue: O[q][d] = O^T/l ; q = q0+wv*32+qs*16+lr, d = dn*16+lg*4+jj
#pragma unroll
    for (int qs = 0; qs < 2; qs++) {
        const float inv = 1.0f / lrun[qs];
        const size_t orow = (size_t)(b * SEQ + q0 + wv * 32 + qs * 16 + lr);
#pragma unroll
        for (int dn = 0; dn < 4; dn++) {
            f16x4 pk;
#pragma unroll
            for (int jj = 0; jj < 4; jj++) pk[jj] = (_Float16)(o[qs][dn][jj] * inv);
            *reinterpret_cast<f16x4*>(&attn[orow * DIM + h * HD2 + dn * 16 + lg * 4]) = pk;
        }
    }
}

extern "C" void kernel_launch(void* const* d_in, const int* in_sizes, int n_in,
                              void* d_out, int out_size, void* d_ws, size_t ws_size,
                              hipStream_t stream) {
    const float* x     = (const float*)d_in[0];
    const float* gamma = (const float*)d_in[1];
    const float* beta  = (const float*)d_in[2];
    const float* w_qkv = (const float*)d_in[3];
    const float* w_out = (const float*)d_in[4];
    const float* b_out = (const float*)d_in[5];
    float* out = (float*)d_out;

    _Float16* ws    = (_Float16*)d_ws;
    _Float16* xn    = ws;                                  // 4096*1024
    _Float16* wqkvT = xn + (size_t)ROWS * DIM;             // 3072*1024
    _Float16* woutT = wqkvT + (size_t)QKVN * DIM;          // 1024*1024
    _Float16* qk    = woutT + (size_t)DIM * DIM;           // 4096*2048
    _Float16* vT    = qk + (size_t)ROWS * 2048;            // (32*64)*2048
    _Float16* attnb = xn;                                  // reuse xn region

    const int pro_blocks = ROWS + (QKVN / 32) * (DIM / 32) + (DIM / 32) * (DIM / 32);
    prologue_kernel<<<pro_blocks, 256, 0, stream>>>(x, gamma, beta, xn, w_qkv, wqkvT, w_out, woutT);
    gemm_qkv_kernel<<<768, 256, 0, stream>>>(xn, wqkvT, qk, vT, DIM);
    attn_fa_kernel<<<512, 256, 0, stream>>>(qk, vT, attnb);
    gemm_out_kernel<<<512, 256, 0, stream>>>(attnb, woutT, out, b_out, DIM, DIM);
}